// Round 1
// baseline (497.545 us; speedup 1.0000x reference)
//
#include <hip/hip_runtime.h>
#include <math.h>

#define HDIM 256
#define BSZ 8
#define FNUM 256
#define SEGS (FNUM * BSZ)   /* 2048 */
#define TWOH 512

__global__ void zero_k(int* __restrict__ cnt) {
    int i = blockIdx.x * blockDim.x + threadIdx.x;
    if (i < SEGS) cnt[i] = 0;
}

__global__ void hist_k(const int* __restrict__ batch, const int* __restrict__ fid,
                       int* __restrict__ cnt, int N) {
    int i = blockIdx.x * blockDim.x + threadIdx.x;
    int stride = gridDim.x * blockDim.x;
    for (; i < N; i += stride) {
        int s = fid[i] * BSZ + batch[i];
        atomicAdd(&cnt[s], 1);
    }
}

// exclusive scan of 2048 counters, one block of 256 threads
__global__ void scan_k(const int* __restrict__ cnt, int* __restrict__ starts,
                       int* __restrict__ running) {
    __shared__ int part[256];
    int t = threadIdx.x;
    int local[8];
    int s = 0;
#pragma unroll
    for (int j = 0; j < 8; ++j) { local[j] = cnt[t * 8 + j]; s += local[j]; }
    part[t] = s;
    __syncthreads();
    for (int off = 1; off < 256; off <<= 1) {
        int v = (t >= off) ? part[t - off] : 0;
        __syncthreads();
        part[t] += v;
        __syncthreads();
    }
    int run = (t == 0) ? 0 : part[t - 1];
#pragma unroll
    for (int j = 0; j < 8; ++j) {
        starts[t * 8 + j] = run;
        running[t * 8 + j] = run;
        run += local[j];
    }
}

__global__ void scatter_k(const int* __restrict__ batch, const int* __restrict__ fid,
                          int* __restrict__ running, int* __restrict__ sorted, int N) {
    int i = blockIdx.x * blockDim.x + threadIdx.x;
    int stride = gridDim.x * blockDim.x;
    for (; i < N; i += stride) {
        int s = fid[i] * BSZ + batch[i];
        int pos = atomicAdd(&running[s], 1);
        sorted[pos] = i;
    }
}

// one block per segment: 256 threads = 64 lanes (float4 over 256 dims) x 4 row groups
__global__ __launch_bounds__(256) void segreduce_k(const float4* __restrict__ x4,
                                                   const int* __restrict__ sorted,
                                                   const int* __restrict__ starts,
                                                   const int* __restrict__ cnt,
                                                   float* __restrict__ feat) {
    __shared__ int sidx[256];
    __shared__ float4 rs[256];
    __shared__ float4 rm[256];
    int s = blockIdx.x;
    int start = starts[s];
    int n = cnt[s];
    int t = threadIdx.x;
    int g = t >> 6;      // row group 0..3
    int l = t & 63;      // float4 lane within row
    float4 as = make_float4(0.f, 0.f, 0.f, 0.f);
    float4 am = make_float4(-INFINITY, -INFINITY, -INFINITY, -INFINITY);

    for (int base = 0; base < n; base += 256) {
        int lim = n - base;
        if (lim > 256) lim = 256;
        if (t < lim) sidx[t] = sorted[start + base + t];
        __syncthreads();
        for (int r = g; r < lim; r += 4) {
            int idx = sidx[r];
            float4 v = x4[(size_t)idx * 64 + l];
            as.x += v.x; as.y += v.y; as.z += v.z; as.w += v.w;
            am.x = fmaxf(am.x, v.x); am.y = fmaxf(am.y, v.y);
            am.z = fmaxf(am.z, v.z); am.w = fmaxf(am.w, v.w);
        }
        __syncthreads();
    }
    rs[t] = as;
    rm[t] = am;
    __syncthreads();
    if (t < 64) {
#pragma unroll
        for (int j = 1; j < 4; ++j) {
            float4 o = rs[t + 64 * j];
            as.x += o.x; as.y += o.y; as.z += o.z; as.w += o.w;
            float4 m = rm[t + 64 * j];
            am.x = fmaxf(am.x, m.x); am.y = fmaxf(am.y, m.y);
            am.z = fmaxf(am.z, m.z); am.w = fmaxf(am.w, m.w);
        }
        float inv = 1.0f / (float)(n > 0 ? n : 1);
        float4 mean = make_float4(as.x * inv, as.y * inv, as.z * inv, as.w * inv);
        if (n == 0) am = make_float4(0.f, 0.f, 0.f, 0.f);
        float4* fm = (float4*)(feat + (size_t)s * TWOH);
        fm[l] = mean;        // dims [0,256)
        fm[64 + l] = am;     // dims [256,512)
    }
}

// func[f,b,h] = relu(sum_k feat[f*B+b][k] * Wf[h][k] + bf[h]); one block per f, thread = h
__global__ __launch_bounds__(256) void funcpool_k(const float* __restrict__ feat,
                                                  const float4* __restrict__ Wf4,
                                                  const float* __restrict__ bfv,
                                                  float* __restrict__ func) {
    __shared__ float fl[BSZ][TWOH];
    int f = blockIdx.x;
    int t = threadIdx.x;
    const float4* src = (const float4*)(feat + (size_t)f * BSZ * TWOH);
    float4* dst = (float4*)&fl[0][0];
    for (int j = t; j < BSZ * TWOH / 4; j += 256) dst[j] = src[j];
    __syncthreads();
    float acc[BSZ];
#pragma unroll
    for (int b = 0; b < BSZ; ++b) acc[b] = 0.f;
    const float4* wrow = Wf4 + (size_t)t * (TWOH / 4);
    for (int k4 = 0; k4 < TWOH / 4; ++k4) {
        float4 w = wrow[k4];
        int k = k4 * 4;
#pragma unroll
        for (int b = 0; b < BSZ; ++b) {
            acc[b] += w.x * fl[b][k] + w.y * fl[b][k + 1] + w.z * fl[b][k + 2] + w.w * fl[b][k + 3];
        }
    }
    float bias = bfv[t];
#pragma unroll
    for (int b = 0; b < BSZ; ++b) {
        float v = acc[b] + bias;
        func[((size_t)f * BSZ + b) * HDIM + t] = v > 0.f ? v : 0.f;
    }
}

// file_feat[b] = [mean_f func[f,b,:], max_f func[f,b,:]]; one block per b, thread = h
__global__ void filereduce_k(const float* __restrict__ func, float* __restrict__ file_feat) {
    int b = blockIdx.x;
    int t = threadIdx.x;
    float s = 0.f, m = -INFINITY;
    for (int f = 0; f < FNUM; ++f) {
        float v = func[((size_t)f * BSZ + b) * HDIM + t];
        s += v;
        m = fmaxf(m, v);
    }
    file_feat[b * TWOH + t] = s * (1.0f / FNUM);
    file_feat[b * TWOH + HDIM + t] = m;
}

// out[b,h] = relu(dot(file_feat[b], Wg[h]) + bg[h]); one block per b, thread = h
__global__ void final_k(const float* __restrict__ file_feat, const float4* __restrict__ Wg4,
                        const float* __restrict__ bg, float* __restrict__ out) {
    __shared__ float fl[TWOH];
    int b = blockIdx.x;
    int t = threadIdx.x;
    for (int j = t; j < TWOH; j += 256) fl[j] = file_feat[b * TWOH + j];
    __syncthreads();
    float acc = 0.f;
    const float4* wr = Wg4 + (size_t)t * (TWOH / 4);
    for (int k4 = 0; k4 < TWOH / 4; ++k4) {
        float4 w = wr[k4];
        int k = k4 * 4;
        acc += w.x * fl[k] + w.y * fl[k + 1] + w.z * fl[k + 2] + w.w * fl[k + 3];
    }
    float v = acc + bg[t];
    out[b * HDIM + t] = v > 0.f ? v : 0.f;
}

extern "C" void kernel_launch(void* const* d_in, const int* in_sizes, int n_in,
                              void* d_out, int out_size, void* d_ws, size_t ws_size,
                              hipStream_t stream) {
    const float* x = (const float*)d_in[0];
    const int* batch = (const int*)d_in[1];
    const int* fid = (const int*)d_in[2];
    const float* Wf = (const float*)d_in[3];
    const float* bfv = (const float*)d_in[4];
    const float* Wg = (const float*)d_in[5];
    const float* bg = (const float*)d_in[6];
    float* out = (float*)d_out;
    int N = in_sizes[1];

    int* cnt = (int*)d_ws;                 // 2048 ints
    int* starts = cnt + SEGS;              // 2048 ints
    int* running = starts + SEGS;          // 2048 ints
    int* sorted = running + SEGS;          // N ints
    float* feat = (float*)(sorted + N);    // SEGS*TWOH f32 (4 MB)
    float* func = feat + (size_t)SEGS * TWOH;   // SEGS*HDIM f32 (2 MB)
    float* file_feat = func + (size_t)SEGS * HDIM;  // BSZ*TWOH f32

    zero_k<<<(SEGS + 255) / 256, 256, 0, stream>>>(cnt);
    int gs = (N + 255) / 256;
    if (gs > 4096) gs = 4096;
    hist_k<<<gs, 256, 0, stream>>>(batch, fid, cnt, N);
    scan_k<<<1, 256, 0, stream>>>(cnt, starts, running);
    scatter_k<<<gs, 256, 0, stream>>>(batch, fid, running, sorted, N);
    segreduce_k<<<SEGS, 256, 0, stream>>>((const float4*)x, sorted, starts, cnt, feat);
    funcpool_k<<<FNUM, 256, 0, stream>>>(feat, (const float4*)Wf, bfv, func);
    filereduce_k<<<BSZ, 256, 0, stream>>>(func, file_feat);
    final_k<<<BSZ, 256, 0, stream>>>(file_feat, (const float4*)Wg, bg, out);
}

// Round 2
// 293.632 us; speedup vs baseline: 1.6945x; 1.6945x over previous
//
#include <hip/hip_runtime.h>
#include <math.h>

#define HDIM 256
#define BSZ 8
#define FNUM 256
#define SEGS (FNUM * BSZ)   /* 2048 */
#define TWOH 512
#define NBLK 512            /* blocks in hist/scatter phases */

// Phase 1: per-block LDS histogram + cache seg ids as u16.
__global__ __launch_bounds__(256) void hist_k(const int* __restrict__ batch,
                                              const int* __restrict__ fid,
                                              unsigned short* __restrict__ seg16,
                                              int* __restrict__ hist_t,
                                              int N, int chunk) {
    __shared__ int h[SEGS];
    int p = blockIdx.x, t = threadIdx.x;
    for (int s = t; s < SEGS; s += 256) h[s] = 0;
    __syncthreads();
    int beg = p * chunk;
    int end = beg + chunk; if (end > N) end = N;
    if (beg < end) {
        int nv = (end - beg) >> 2;
        const int4* b4 = (const int4*)(batch + beg);
        const int4* f4 = (const int4*)(fid + beg);
        ushort4* s4 = (ushort4*)(seg16 + beg);
        for (int j = t; j < nv; j += 256) {
            int4 bb = b4[j];
            int4 ff = f4[j];
            int s0 = ff.x * BSZ + bb.x;
            int s1 = ff.y * BSZ + bb.y;
            int s2 = ff.z * BSZ + bb.z;
            int s3 = ff.w * BSZ + bb.w;
            s4[j] = make_ushort4((unsigned short)s0, (unsigned short)s1,
                                 (unsigned short)s2, (unsigned short)s3);
            atomicAdd(&h[s0], 1);
            atomicAdd(&h[s1], 1);
            atomicAdd(&h[s2], 1);
            atomicAdd(&h[s3], 1);
        }
        for (int i = beg + (nv << 2) + t; i < end; i += 256) {
            int s = fid[i] * BSZ + batch[i];
            seg16[i] = (unsigned short)s;
            atomicAdd(&h[s], 1);
        }
    }
    __syncthreads();
    for (int s = t; s < SEGS; s += 256)
        hist_t[(size_t)s * NBLK + p] = h[s];
}

// Phase 2a: per-segment scan over the NBLK per-block counts (in place) + totals.
__global__ __launch_bounds__(64) void segscan_k(int* __restrict__ hist_t,
                                                int* __restrict__ cnt) {
    int s = blockIdx.x * 64 + threadIdx.x;
    if (s >= SEGS) return;
    int4* row = (int4*)(hist_t + (size_t)s * NBLK);
    int run = 0;
#pragma unroll 4
    for (int j = 0; j < NBLK / 4; ++j) {
        int4 v = row[j];
        int4 o;
        o.x = run; run += v.x;
        o.y = run; run += v.y;
        o.z = run; run += v.z;
        o.w = run; run += v.w;
        row[j] = o;
    }
    cnt[s] = run;
}

// Phase 2b: exclusive scan of 2048 totals -> segment starts. One block.
__global__ void scan_k(const int* __restrict__ cnt, int* __restrict__ starts) {
    __shared__ int part[256];
    int t = threadIdx.x;
    int local[8];
    int s = 0;
#pragma unroll
    for (int j = 0; j < 8; ++j) { local[j] = cnt[t * 8 + j]; s += local[j]; }
    part[t] = s;
    __syncthreads();
    for (int off = 1; off < 256; off <<= 1) {
        int v = (t >= off) ? part[t - off] : 0;
        __syncthreads();
        part[t] += v;
        __syncthreads();
    }
    int run = (t == 0) ? 0 : part[t - 1];
#pragma unroll
    for (int j = 0; j < 8; ++j) {
        starts[t * 8 + j] = run;
        run += local[j];
    }
}

// Phase 3: deterministic-base scatter; LDS atomics only.
__global__ __launch_bounds__(256) void scatter_k(const unsigned short* __restrict__ seg16,
                                                 const int* __restrict__ hist_t,
                                                 const int* __restrict__ starts,
                                                 int* __restrict__ sorted,
                                                 int N, int chunk) {
    __shared__ int off[SEGS];
    int p = blockIdx.x, t = threadIdx.x;
    for (int s = t; s < SEGS; s += 256)
        off[s] = starts[s] + hist_t[(size_t)s * NBLK + p];
    __syncthreads();
    int beg = p * chunk;
    int end = beg + chunk; if (end > N) end = N;
    if (beg < end) {
        int nv = (end - beg) >> 2;
        const ushort4* s4 = (const ushort4*)(seg16 + beg);
        for (int j = t; j < nv; j += 256) {
            ushort4 ss = s4[j];
            int i0 = beg + 4 * j;
            sorted[atomicAdd(&off[ss.x], 1)] = i0;
            sorted[atomicAdd(&off[ss.y], 1)] = i0 + 1;
            sorted[atomicAdd(&off[ss.z], 1)] = i0 + 2;
            sorted[atomicAdd(&off[ss.w], 1)] = i0 + 3;
        }
        for (int i = beg + (nv << 2) + t; i < end; i += 256)
            sorted[atomicAdd(&off[seg16[i]], 1)] = i;
    }
}

// one block per segment: 256 threads = 64 lanes (float4 over 256 dims) x 4 row groups
__global__ __launch_bounds__(256) void segreduce_k(const float4* __restrict__ x4,
                                                   const int* __restrict__ sorted,
                                                   const int* __restrict__ starts,
                                                   const int* __restrict__ cnt,
                                                   float* __restrict__ feat) {
    __shared__ int sidx[256];
    __shared__ float4 rs[256];
    __shared__ float4 rm[256];
    int s = blockIdx.x;
    int start = starts[s];
    int n = cnt[s];
    int t = threadIdx.x;
    int g = t >> 6;
    int l = t & 63;
    float4 as = make_float4(0.f, 0.f, 0.f, 0.f);
    float4 am = make_float4(-INFINITY, -INFINITY, -INFINITY, -INFINITY);

    for (int base = 0; base < n; base += 256) {
        int lim = n - base;
        if (lim > 256) lim = 256;
        if (t < lim) sidx[t] = sorted[start + base + t];
        __syncthreads();
        for (int r = g; r < lim; r += 4) {
            int idx = sidx[r];
            float4 v = x4[(size_t)idx * 64 + l];
            as.x += v.x; as.y += v.y; as.z += v.z; as.w += v.w;
            am.x = fmaxf(am.x, v.x); am.y = fmaxf(am.y, v.y);
            am.z = fmaxf(am.z, v.z); am.w = fmaxf(am.w, v.w);
        }
        __syncthreads();
    }
    rs[t] = as;
    rm[t] = am;
    __syncthreads();
    if (t < 64) {
#pragma unroll
        for (int j = 1; j < 4; ++j) {
            float4 o = rs[t + 64 * j];
            as.x += o.x; as.y += o.y; as.z += o.z; as.w += o.w;
            float4 m = rm[t + 64 * j];
            am.x = fmaxf(am.x, m.x); am.y = fmaxf(am.y, m.y);
            am.z = fmaxf(am.z, m.z); am.w = fmaxf(am.w, m.w);
        }
        float inv = 1.0f / (float)(n > 0 ? n : 1);
        float4 mean = make_float4(as.x * inv, as.y * inv, as.z * inv, as.w * inv);
        if (n == 0) am = make_float4(0.f, 0.f, 0.f, 0.f);
        float4* fm = (float4*)(feat + (size_t)s * TWOH);
        fm[l] = mean;
        fm[64 + l] = am;
    }
}

// func[f,b,h] = relu(sum_k feat[f*B+b][k] * Wf[h][k] + bf[h])
__global__ __launch_bounds__(256) void funcpool_k(const float* __restrict__ feat,
                                                  const float4* __restrict__ Wf4,
                                                  const float* __restrict__ bfv,
                                                  float* __restrict__ func) {
    __shared__ float fl[BSZ][TWOH];
    int f = blockIdx.x;
    int t = threadIdx.x;
    const float4* src = (const float4*)(feat + (size_t)f * BSZ * TWOH);
    float4* dst = (float4*)&fl[0][0];
    for (int j = t; j < BSZ * TWOH / 4; j += 256) dst[j] = src[j];
    __syncthreads();
    float acc[BSZ];
#pragma unroll
    for (int b = 0; b < BSZ; ++b) acc[b] = 0.f;
    const float4* wrow = Wf4 + (size_t)t * (TWOH / 4);
    for (int k4 = 0; k4 < TWOH / 4; ++k4) {
        float4 w = wrow[k4];
        int k = k4 * 4;
#pragma unroll
        for (int b = 0; b < BSZ; ++b) {
            acc[b] += w.x * fl[b][k] + w.y * fl[b][k + 1] + w.z * fl[b][k + 2] + w.w * fl[b][k + 3];
        }
    }
    float bias = bfv[t];
#pragma unroll
    for (int b = 0; b < BSZ; ++b) {
        float v = acc[b] + bias;
        func[((size_t)f * BSZ + b) * HDIM + t] = v > 0.f ? v : 0.f;
    }
}

__global__ void filereduce_k(const float* __restrict__ func, float* __restrict__ file_feat) {
    int b = blockIdx.x;
    int t = threadIdx.x;
    float s = 0.f, m = -INFINITY;
    for (int f = 0; f < FNUM; ++f) {
        float v = func[((size_t)f * BSZ + b) * HDIM + t];
        s += v;
        m = fmaxf(m, v);
    }
    file_feat[b * TWOH + t] = s * (1.0f / FNUM);
    file_feat[b * TWOH + HDIM + t] = m;
}

__global__ void final_k(const float* __restrict__ file_feat, const float4* __restrict__ Wg4,
                        const float* __restrict__ bg, float* __restrict__ out) {
    __shared__ float fl[TWOH];
    int b = blockIdx.x;
    int t = threadIdx.x;
    for (int j = t; j < TWOH; j += 256) fl[j] = file_feat[b * TWOH + j];
    __syncthreads();
    float acc = 0.f;
    const float4* wr = Wg4 + (size_t)t * (TWOH / 4);
    for (int k4 = 0; k4 < TWOH / 4; ++k4) {
        float4 w = wr[k4];
        int k = k4 * 4;
        acc += w.x * fl[k] + w.y * fl[k + 1] + w.z * fl[k + 2] + w.w * fl[k + 3];
    }
    float v = acc + bg[t];
    out[b * HDIM + t] = v > 0.f ? v : 0.f;
}

extern "C" void kernel_launch(void* const* d_in, const int* in_sizes, int n_in,
                              void* d_out, int out_size, void* d_ws, size_t ws_size,
                              hipStream_t stream) {
    const float* x = (const float*)d_in[0];
    const int* batch = (const int*)d_in[1];
    const int* fid = (const int*)d_in[2];
    const float* Wf = (const float*)d_in[3];
    const float* bfv = (const float*)d_in[4];
    const float* Wg = (const float*)d_in[5];
    const float* bg = (const float*)d_in[6];
    float* out = (float*)d_out;
    int N = in_sizes[1];

    int* sorted = (int*)d_ws;                                   // N ints
    int* hist_t = sorted + N;                                   // SEGS*NBLK ints (4 MB)
    int* starts = hist_t + (size_t)SEGS * NBLK;                 // SEGS
    int* cnt = starts + SEGS;                                   // SEGS
    float* feat = (float*)(cnt + SEGS);                         // SEGS*TWOH
    float* func = feat + (size_t)SEGS * TWOH;                   // SEGS*HDIM
    float* file_feat = func + (size_t)SEGS * HDIM;              // BSZ*TWOH
    unsigned short* seg16 = (unsigned short*)(file_feat + BSZ * TWOH);  // N u16

    int chunk = ((N + NBLK - 1) / NBLK + 3) & ~3;  // multiple of 4 for int4 paths

    hist_k<<<NBLK, 256, 0, stream>>>(batch, fid, seg16, hist_t, N, chunk);
    segscan_k<<<SEGS / 64, 64, 0, stream>>>(hist_t, cnt);
    scan_k<<<1, 256, 0, stream>>>(cnt, starts);
    scatter_k<<<NBLK, 256, 0, stream>>>(seg16, hist_t, starts, sorted, N, chunk);
    segreduce_k<<<SEGS, 256, 0, stream>>>((const float4*)x, sorted, starts, cnt, feat);
    funcpool_k<<<FNUM, 256, 0, stream>>>(feat, (const float4*)Wf, bfv, func);
    filereduce_k<<<BSZ, 256, 0, stream>>>(func, file_feat);
    final_k<<<BSZ, 256, 0, stream>>>(file_feat, (const float4*)Wg, bg, out);
}

// Round 3
// 291.826 us; speedup vs baseline: 1.7049x; 1.0062x over previous
//
#include <hip/hip_runtime.h>
#include <math.h>

#define HDIM 256
#define BSZ 8
#define FNUM 256
#define SEGS (FNUM * BSZ)   /* 2048 */
#define TWOH 512
#define NBLK 512            /* blocks in hist/scatter phases */

// Phase 1: per-block LDS histogram + cache seg ids as u16.
__global__ __launch_bounds__(256) void hist_k(const int* __restrict__ batch,
                                              const int* __restrict__ fid,
                                              unsigned short* __restrict__ seg16,
                                              int* __restrict__ hist_t,
                                              int N, int chunk) {
    __shared__ int h[SEGS];
    int p = blockIdx.x, t = threadIdx.x;
    for (int s = t; s < SEGS; s += 256) h[s] = 0;
    __syncthreads();
    int beg = p * chunk;
    int end = beg + chunk; if (end > N) end = N;
    if (beg < end) {
        int nv = (end - beg) >> 2;
        const int4* b4 = (const int4*)(batch + beg);
        const int4* f4 = (const int4*)(fid + beg);
        ushort4* s4 = (ushort4*)(seg16 + beg);
        for (int j = t; j < nv; j += 256) {
            int4 bb = b4[j];
            int4 ff = f4[j];
            int s0 = ff.x * BSZ + bb.x;
            int s1 = ff.y * BSZ + bb.y;
            int s2 = ff.z * BSZ + bb.z;
            int s3 = ff.w * BSZ + bb.w;
            s4[j] = make_ushort4((unsigned short)s0, (unsigned short)s1,
                                 (unsigned short)s2, (unsigned short)s3);
            atomicAdd(&h[s0], 1);
            atomicAdd(&h[s1], 1);
            atomicAdd(&h[s2], 1);
            atomicAdd(&h[s3], 1);
        }
        for (int i = beg + (nv << 2) + t; i < end; i += 256) {
            int s = fid[i] * BSZ + batch[i];
            seg16[i] = (unsigned short)s;
            atomicAdd(&h[s], 1);
        }
    }
    __syncthreads();
    for (int s = t; s < SEGS; s += 256)
        hist_t[(size_t)s * NBLK + p] = h[s];
}

// Phase 2a: one WAVE per segment; lane l owns 8 contiguous block-counts.
// Coalesced 2 KB reads per wave + shfl-based wave scan.
__global__ __launch_bounds__(256) void segscan_k(int* __restrict__ hist_t,
                                                 int* __restrict__ cnt) {
    int wid = (int)((blockIdx.x * 256 + threadIdx.x) >> 6);  // segment id
    int lane = threadIdx.x & 63;
    if (wid >= SEGS) return;
    int4* row = (int4*)(hist_t + (size_t)wid * NBLK + lane * 8);
    int4 a = row[0], b = row[1];
    int lsum = a.x + a.y + a.z + a.w + b.x + b.y + b.z + b.w;
    int inc = lsum;
#pragma unroll
    for (int off = 1; off < 64; off <<= 1) {
        int v = __shfl_up(inc, off, 64);
        if (lane >= off) inc += v;
    }
    int r = inc - lsum;  // exclusive base for this lane
    int4 oa, ob;
    oa.x = r; r += a.x; oa.y = r; r += a.y; oa.z = r; r += a.z; oa.w = r; r += a.w;
    ob.x = r; r += b.x; ob.y = r; r += b.y; ob.z = r; r += b.z; ob.w = r; r += b.w;
    row[0] = oa; row[1] = ob;
    if (lane == 63) cnt[wid] = inc;
}

// Phase 2b: exclusive scan of 2048 totals -> segment starts. One block.
__global__ void scan_k(const int* __restrict__ cnt, int* __restrict__ starts) {
    __shared__ int part[256];
    int t = threadIdx.x;
    int local[8];
    int s = 0;
#pragma unroll
    for (int j = 0; j < 8; ++j) { local[j] = cnt[t * 8 + j]; s += local[j]; }
    part[t] = s;
    __syncthreads();
    for (int off = 1; off < 256; off <<= 1) {
        int v = (t >= off) ? part[t - off] : 0;
        __syncthreads();
        part[t] += v;
        __syncthreads();
    }
    int run = (t == 0) ? 0 : part[t - 1];
#pragma unroll
    for (int j = 0; j < 8; ++j) {
        starts[t * 8 + j] = run;
        run += local[j];
    }
}

// Phase 3: deterministic-base scatter; LDS atomics only.
__global__ __launch_bounds__(256) void scatter_k(const unsigned short* __restrict__ seg16,
                                                 const int* __restrict__ hist_t,
                                                 const int* __restrict__ starts,
                                                 int* __restrict__ sorted,
                                                 int N, int chunk) {
    __shared__ int off[SEGS];
    int p = blockIdx.x, t = threadIdx.x;
    for (int s = t; s < SEGS; s += 256)
        off[s] = starts[s] + hist_t[(size_t)s * NBLK + p];
    __syncthreads();
    int beg = p * chunk;
    int end = beg + chunk; if (end > N) end = N;
    if (beg < end) {
        int nv = (end - beg) >> 2;
        const ushort4* s4 = (const ushort4*)(seg16 + beg);
        for (int j = t; j < nv; j += 256) {
            ushort4 ss = s4[j];
            int i0 = beg + 4 * j;
            sorted[atomicAdd(&off[ss.x], 1)] = i0;
            sorted[atomicAdd(&off[ss.y], 1)] = i0 + 1;
            sorted[atomicAdd(&off[ss.z], 1)] = i0 + 2;
            sorted[atomicAdd(&off[ss.w], 1)] = i0 + 3;
        }
        for (int i = beg + (nv << 2) + t; i < end; i += 256)
            sorted[atomicAdd(&off[seg16[i]], 1)] = i;
    }
}

// one block per segment: 256 threads = 64 lanes (float4 over 256 dims) x 4 row groups.
// 2-row unroll for more outstanding 1 KB gathers.
__global__ __launch_bounds__(256) void segreduce_k(const float4* __restrict__ x4,
                                                   const int* __restrict__ sorted,
                                                   const int* __restrict__ starts,
                                                   const int* __restrict__ cnt,
                                                   float* __restrict__ feat) {
    __shared__ int sidx[256];
    __shared__ float4 rs[256];
    __shared__ float4 rm[256];
    int s = blockIdx.x;
    int start = starts[s];
    int n = cnt[s];
    int t = threadIdx.x;
    int g = t >> 6;
    int l = t & 63;
    float4 as = make_float4(0.f, 0.f, 0.f, 0.f);
    float4 am = make_float4(-INFINITY, -INFINITY, -INFINITY, -INFINITY);

    for (int base = 0; base < n; base += 256) {
        int lim = n - base;
        if (lim > 256) lim = 256;
        if (t < lim) sidx[t] = sorted[start + base + t];
        __syncthreads();
        int r = g;
        for (; r + 4 < lim; r += 8) {
            int i0 = sidx[r];
            int i1 = sidx[r + 4];
            float4 v0 = x4[(size_t)i0 * 64 + l];
            float4 v1 = x4[(size_t)i1 * 64 + l];
            as.x += v0.x; as.y += v0.y; as.z += v0.z; as.w += v0.w;
            am.x = fmaxf(am.x, v0.x); am.y = fmaxf(am.y, v0.y);
            am.z = fmaxf(am.z, v0.z); am.w = fmaxf(am.w, v0.w);
            as.x += v1.x; as.y += v1.y; as.z += v1.z; as.w += v1.w;
            am.x = fmaxf(am.x, v1.x); am.y = fmaxf(am.y, v1.y);
            am.z = fmaxf(am.z, v1.z); am.w = fmaxf(am.w, v1.w);
        }
        if (r < lim) {
            int i0 = sidx[r];
            float4 v0 = x4[(size_t)i0 * 64 + l];
            as.x += v0.x; as.y += v0.y; as.z += v0.z; as.w += v0.w;
            am.x = fmaxf(am.x, v0.x); am.y = fmaxf(am.y, v0.y);
            am.z = fmaxf(am.z, v0.z); am.w = fmaxf(am.w, v0.w);
        }
        __syncthreads();
    }
    rs[t] = as;
    rm[t] = am;
    __syncthreads();
    if (t < 64) {
#pragma unroll
        for (int j = 1; j < 4; ++j) {
            float4 o = rs[t + 64 * j];
            as.x += o.x; as.y += o.y; as.z += o.z; as.w += o.w;
            float4 m = rm[t + 64 * j];
            am.x = fmaxf(am.x, m.x); am.y = fmaxf(am.y, m.y);
            am.z = fmaxf(am.z, m.z); am.w = fmaxf(am.w, m.w);
        }
        float inv = 1.0f / (float)(n > 0 ? n : 1);
        float4 mean = make_float4(as.x * inv, as.y * inv, as.z * inv, as.w * inv);
        if (n == 0) am = make_float4(0.f, 0.f, 0.f, 0.f);
        float4* fm = (float4*)(feat + (size_t)s * TWOH);
        fm[l] = mean;
        fm[64 + l] = am;
    }
}

// func[f,b,h] = relu(sum_k feat[f*B+b][k] * Wf[h][k] + bf[h])
__global__ __launch_bounds__(256) void funcpool_k(const float* __restrict__ feat,
                                                  const float4* __restrict__ Wf4,
                                                  const float* __restrict__ bfv,
                                                  float* __restrict__ func) {
    __shared__ float fl[BSZ][TWOH];
    int f = blockIdx.x;
    int t = threadIdx.x;
    const float4* src = (const float4*)(feat + (size_t)f * BSZ * TWOH);
    float4* dst = (float4*)&fl[0][0];
    for (int j = t; j < BSZ * TWOH / 4; j += 256) dst[j] = src[j];
    __syncthreads();
    float acc[BSZ];
#pragma unroll
    for (int b = 0; b < BSZ; ++b) acc[b] = 0.f;
    const float4* wrow = Wf4 + (size_t)t * (TWOH / 4);
    for (int k4 = 0; k4 < TWOH / 4; ++k4) {
        float4 w = wrow[k4];
        int k = k4 * 4;
#pragma unroll
        for (int b = 0; b < BSZ; ++b) {
            acc[b] += w.x * fl[b][k] + w.y * fl[b][k + 1] + w.z * fl[b][k + 2] + w.w * fl[b][k + 3];
        }
    }
    float bias = bfv[t];
#pragma unroll
    for (int b = 0; b < BSZ; ++b) {
        float v = acc[b] + bias;
        func[((size_t)f * BSZ + b) * HDIM + t] = v > 0.f ? v : 0.f;
    }
}

// Fused: file_feat[b] = [mean_f func, max_f func] then out[b]=relu(file_feat@Wg^T+bg).
// One block per b (8 blocks), thread = h.
__global__ __launch_bounds__(256) void filefinal_k(const float* __restrict__ func,
                                                   const float4* __restrict__ Wg4,
                                                   const float* __restrict__ bg,
                                                   float* __restrict__ out) {
    __shared__ float fl[TWOH];
    int b = blockIdx.x;
    int t = threadIdx.x;
    float s = 0.f, m = -INFINITY;
#pragma unroll 4
    for (int f = 0; f < FNUM; ++f) {
        float v = func[((size_t)f * BSZ + b) * HDIM + t];
        s += v;
        m = fmaxf(m, v);
    }
    fl[t] = s * (1.0f / FNUM);
    fl[HDIM + t] = m;
    __syncthreads();
    float acc = 0.f;
    const float4* wr = Wg4 + (size_t)t * (TWOH / 4);
    for (int k4 = 0; k4 < TWOH / 4; ++k4) {
        float4 w = wr[k4];
        int k = k4 * 4;
        acc += w.x * fl[k] + w.y * fl[k + 1] + w.z * fl[k + 2] + w.w * fl[k + 3];
    }
    float v = acc + bg[t];
    out[b * HDIM + t] = v > 0.f ? v : 0.f;
}

extern "C" void kernel_launch(void* const* d_in, const int* in_sizes, int n_in,
                              void* d_out, int out_size, void* d_ws, size_t ws_size,
                              hipStream_t stream) {
    const float* x = (const float*)d_in[0];
    const int* batch = (const int*)d_in[1];
    const int* fid = (const int*)d_in[2];
    const float* Wf = (const float*)d_in[3];
    const float* bfv = (const float*)d_in[4];
    const float* Wg = (const float*)d_in[5];
    const float* bg = (const float*)d_in[6];
    float* out = (float*)d_out;
    int N = in_sizes[1];

    int* sorted = (int*)d_ws;                                   // N ints
    int* hist_t = sorted + N;                                   // SEGS*NBLK ints (4 MB)
    int* starts = hist_t + (size_t)SEGS * NBLK;                 // SEGS
    int* cnt = starts + SEGS;                                   // SEGS
    float* feat = (float*)(cnt + SEGS);                         // SEGS*TWOH
    float* func = feat + (size_t)SEGS * TWOH;                   // SEGS*HDIM
    unsigned short* seg16 = (unsigned short*)(func + (size_t)SEGS * HDIM);  // N u16

    int chunk = ((N + NBLK - 1) / NBLK + 3) & ~3;  // multiple of 4 for int4 paths

    hist_k<<<NBLK, 256, 0, stream>>>(batch, fid, seg16, hist_t, N, chunk);
    segscan_k<<<SEGS / 4, 256, 0, stream>>>(hist_t, cnt);
    scan_k<<<1, 256, 0, stream>>>(cnt, starts);
    scatter_k<<<NBLK, 256, 0, stream>>>(seg16, hist_t, starts, sorted, N, chunk);
    segreduce_k<<<SEGS, 256, 0, stream>>>((const float4*)x, sorted, starts, cnt, feat);
    funcpool_k<<<FNUM, 256, 0, stream>>>(feat, (const float4*)Wf, bfv, func);
    filefinal_k<<<BSZ, 256, 0, stream>>>(func, (const float4*)Wg, bg, out);
}

// Round 5
// 260.252 us; speedup vs baseline: 1.9118x; 1.1213x over previous
//
#include <hip/hip_runtime.h>
#include <math.h>

#define HDIM 256
#define BSZ 8
#define FNUM 256
#define SEGS (FNUM * BSZ)   /* 2048 */
#define TWOH 512
#define NBLK 256            /* blocks in hist/scatter phases */

typedef float f32x4 __attribute__((ext_vector_type(4)));

// Phase 1: per-block LDS histogram + cache seg ids as u16.
__global__ __launch_bounds__(256) void hist_k(const int* __restrict__ batch,
                                              const int* __restrict__ fid,
                                              unsigned short* __restrict__ seg16,
                                              int* __restrict__ hist_t,
                                              int N, int chunk) {
    __shared__ int h[SEGS];
    int p = blockIdx.x, t = threadIdx.x;
    for (int s = t; s < SEGS; s += 256) h[s] = 0;
    __syncthreads();
    int beg = p * chunk;
    int end = beg + chunk; if (end > N) end = N;
    if (beg < end) {
        int nv = (end - beg) >> 2;
        const int4* b4 = (const int4*)(batch + beg);
        const int4* f4 = (const int4*)(fid + beg);
        ushort4* s4 = (ushort4*)(seg16 + beg);
        for (int j = t; j < nv; j += 256) {
            int4 bb = b4[j];
            int4 ff = f4[j];
            int s0 = ff.x * BSZ + bb.x;
            int s1 = ff.y * BSZ + bb.y;
            int s2 = ff.z * BSZ + bb.z;
            int s3 = ff.w * BSZ + bb.w;
            s4[j] = make_ushort4((unsigned short)s0, (unsigned short)s1,
                                 (unsigned short)s2, (unsigned short)s3);
            atomicAdd(&h[s0], 1);
            atomicAdd(&h[s1], 1);
            atomicAdd(&h[s2], 1);
            atomicAdd(&h[s3], 1);
        }
        for (int i = beg + (nv << 2) + t; i < end; i += 256) {
            int s = fid[i] * BSZ + batch[i];
            seg16[i] = (unsigned short)s;
            atomicAdd(&h[s], 1);
        }
    }
    __syncthreads();
    for (int s = t; s < SEGS; s += 256)
        hist_t[(size_t)s * NBLK + p] = h[s];
}

// Phase 2a: one WAVE per segment; lane l owns 4 contiguous block-counts (int4).
__global__ __launch_bounds__(256) void segscan_k(int* __restrict__ hist_t,
                                                 int* __restrict__ cnt) {
    int wid = (int)((blockIdx.x * 256 + threadIdx.x) >> 6);  // segment id
    int lane = threadIdx.x & 63;
    if (wid >= SEGS) return;
    int4* row = (int4*)(hist_t + (size_t)wid * NBLK) + lane;
    int4 a = *row;
    int lsum = a.x + a.y + a.z + a.w;
    int inc = lsum;
#pragma unroll
    for (int off = 1; off < 64; off <<= 1) {
        int v = __shfl_up(inc, off, 64);
        if (lane >= off) inc += v;
    }
    int r = inc - lsum;  // exclusive base for this lane
    int4 oa;
    oa.x = r; r += a.x; oa.y = r; r += a.y; oa.z = r; r += a.z; oa.w = r; r += a.w;
    *row = oa;
    if (lane == 63) cnt[wid] = inc;
}

// Phase 2b: exclusive scan of 2048 totals -> segment starts. One block.
__global__ void scan_k(const int* __restrict__ cnt, int* __restrict__ starts) {
    __shared__ int part[256];
    int t = threadIdx.x;
    int local[8];
    int s = 0;
#pragma unroll
    for (int j = 0; j < 8; ++j) { local[j] = cnt[t * 8 + j]; s += local[j]; }
    part[t] = s;
    __syncthreads();
    for (int off = 1; off < 256; off <<= 1) {
        int v = (t >= off) ? part[t - off] : 0;
        __syncthreads();
        part[t] += v;
        __syncthreads();
    }
    int run = (t == 0) ? 0 : part[t - 1];
#pragma unroll
    for (int j = 0; j < 8; ++j) {
        starts[t * 8 + j] = run;
        run += local[j];
    }
}

// Phase 3: deterministic-base scatter; LDS atomics only.
__global__ __launch_bounds__(256) void scatter_k(const unsigned short* __restrict__ seg16,
                                                 const int* __restrict__ hist_t,
                                                 const int* __restrict__ starts,
                                                 int* __restrict__ sorted,
                                                 int N, int chunk) {
    __shared__ int off[SEGS];
    int p = blockIdx.x, t = threadIdx.x;
    for (int s = t; s < SEGS; s += 256)
        off[s] = starts[s] + hist_t[(size_t)s * NBLK + p];
    __syncthreads();
    int beg = p * chunk;
    int end = beg + chunk; if (end > N) end = N;
    if (beg < end) {
        int nv = (end - beg) >> 2;
        const ushort4* s4 = (const ushort4*)(seg16 + beg);
        for (int j = t; j < nv; j += 256) {
            ushort4 ss = s4[j];
            int i0 = beg + 4 * j;
            sorted[atomicAdd(&off[ss.x], 1)] = i0;
            sorted[atomicAdd(&off[ss.y], 1)] = i0 + 1;
            sorted[atomicAdd(&off[ss.z], 1)] = i0 + 2;
            sorted[atomicAdd(&off[ss.w], 1)] = i0 + 3;
        }
        for (int i = beg + (nv << 2) + t; i < end; i += 256)
            sorted[atomicAdd(&off[seg16[i]], 1)] = i;
    }
}

// one block per segment: 256 threads = 64 lanes (float4 over 256 dims) x 4 row groups.
// 4-row unroll: 4 outstanding 1 KB wave-gathers; nontemporal x loads (zero reuse).
__global__ __launch_bounds__(256, 8) void segreduce_k(const f32x4* __restrict__ x4,
                                                      const int* __restrict__ sorted,
                                                      const int* __restrict__ starts,
                                                      const int* __restrict__ cnt,
                                                      float* __restrict__ feat) {
    __shared__ int sidx[256];
    __shared__ f32x4 rs[256];
    __shared__ f32x4 rm[256];
    int s = blockIdx.x;
    int start = starts[s];
    int n = cnt[s];
    int t = threadIdx.x;
    int g = t >> 6;
    int l = t & 63;
    f32x4 as = (f32x4)(0.f);
    f32x4 am = (f32x4)(-INFINITY);

    for (int base = 0; base < n; base += 256) {
        int lim = n - base;
        if (lim > 256) lim = 256;
        if (t < lim) sidx[t] = sorted[start + base + t];
        __syncthreads();
        int r = g;
        for (; r + 12 < lim; r += 16) {
            int i0 = sidx[r];
            int i1 = sidx[r + 4];
            int i2 = sidx[r + 8];
            int i3 = sidx[r + 12];
            f32x4 v0 = __builtin_nontemporal_load(&x4[(size_t)i0 * 64 + l]);
            f32x4 v1 = __builtin_nontemporal_load(&x4[(size_t)i1 * 64 + l]);
            f32x4 v2 = __builtin_nontemporal_load(&x4[(size_t)i2 * 64 + l]);
            f32x4 v3 = __builtin_nontemporal_load(&x4[(size_t)i3 * 64 + l]);
            as += v0;
            am = __builtin_elementwise_max(am, v0);
            as += v1;
            am = __builtin_elementwise_max(am, v1);
            as += v2;
            am = __builtin_elementwise_max(am, v2);
            as += v3;
            am = __builtin_elementwise_max(am, v3);
        }
        for (; r < lim; r += 4) {
            int i0 = sidx[r];
            f32x4 v0 = __builtin_nontemporal_load(&x4[(size_t)i0 * 64 + l]);
            as += v0;
            am = __builtin_elementwise_max(am, v0);
        }
        __syncthreads();
    }
    rs[t] = as;
    rm[t] = am;
    __syncthreads();
    if (t < 64) {
#pragma unroll
        for (int j = 1; j < 4; ++j) {
            as += rs[t + 64 * j];
            am = __builtin_elementwise_max(am, rm[t + 64 * j]);
        }
        float inv = 1.0f / (float)(n > 0 ? n : 1);
        f32x4 mean = as * inv;
        if (n == 0) am = (f32x4)(0.f);
        f32x4* fm = (f32x4*)(feat + (size_t)s * TWOH);
        fm[l] = mean;
        fm[64 + l] = am;
    }
}

// func[f,b,h] = relu(sum_k feat[f*B+b][k] * Wf[h][k] + bf[h])
__global__ __launch_bounds__(256) void funcpool_k(const float* __restrict__ feat,
                                                  const float4* __restrict__ Wf4,
                                                  const float* __restrict__ bfv,
                                                  float* __restrict__ func) {
    __shared__ float fl[BSZ][TWOH];
    int f = blockIdx.x;
    int t = threadIdx.x;
    const float4* src = (const float4*)(feat + (size_t)f * BSZ * TWOH);
    float4* dst = (float4*)&fl[0][0];
    for (int j = t; j < BSZ * TWOH / 4; j += 256) dst[j] = src[j];
    __syncthreads();
    float acc[BSZ];
#pragma unroll
    for (int b = 0; b < BSZ; ++b) acc[b] = 0.f;
    const float4* wrow = Wf4 + (size_t)t * (TWOH / 4);
    for (int k4 = 0; k4 < TWOH / 4; ++k4) {
        float4 w = wrow[k4];
        int k = k4 * 4;
#pragma unroll
        for (int b = 0; b < BSZ; ++b) {
            acc[b] += w.x * fl[b][k] + w.y * fl[b][k + 1] + w.z * fl[b][k + 2] + w.w * fl[b][k + 3];
        }
    }
    float bias = bfv[t];
#pragma unroll
    for (int b = 0; b < BSZ; ++b) {
        float v = acc[b] + bias;
        func[((size_t)f * BSZ + b) * HDIM + t] = v > 0.f ? v : 0.f;
    }
}

// Fused: file_feat[b] = [mean_f func, max_f func] then out[b]=relu(file_feat@Wg^T+bg).
__global__ __launch_bounds__(256) void filefinal_k(const float* __restrict__ func,
                                                   const float4* __restrict__ Wg4,
                                                   const float* __restrict__ bg,
                                                   float* __restrict__ out) {
    __shared__ float fl[TWOH];
    int b = blockIdx.x;
    int t = threadIdx.x;
    float s = 0.f, m = -INFINITY;
#pragma unroll 4
    for (int f = 0; f < FNUM; ++f) {
        float v = func[((size_t)f * BSZ + b) * HDIM + t];
        s += v;
        m = fmaxf(m, v);
    }
    fl[t] = s * (1.0f / FNUM);
    fl[HDIM + t] = m;
    __syncthreads();
    float acc = 0.f;
    const float4* wr = Wg4 + (size_t)t * (TWOH / 4);
    for (int k4 = 0; k4 < TWOH / 4; ++k4) {
        float4 w = wr[k4];
        int k = k4 * 4;
        acc += w.x * fl[k] + w.y * fl[k + 1] + w.z * fl[k + 2] + w.w * fl[k + 3];
    }
    float v = acc + bg[t];
    out[b * HDIM + t] = v > 0.f ? v : 0.f;
}

extern "C" void kernel_launch(void* const* d_in, const int* in_sizes, int n_in,
                              void* d_out, int out_size, void* d_ws, size_t ws_size,
                              hipStream_t stream) {
    const float* x = (const float*)d_in[0];
    const int* batch = (const int*)d_in[1];
    const int* fid = (const int*)d_in[2];
    const float* Wf = (const float*)d_in[3];
    const float* bfv = (const float*)d_in[4];
    const float* Wg = (const float*)d_in[5];
    const float* bg = (const float*)d_in[6];
    float* out = (float*)d_out;
    int N = in_sizes[1];

    int* sorted = (int*)d_ws;                                   // N ints
    int* hist_t = sorted + N;                                   // SEGS*NBLK ints (2 MB)
    int* starts = hist_t + (size_t)SEGS * NBLK;                 // SEGS
    int* cnt = starts + SEGS;                                   // SEGS
    float* feat = (float*)(cnt + SEGS);                         // SEGS*TWOH
    float* func = feat + (size_t)SEGS * TWOH;                   // SEGS*HDIM
    unsigned short* seg16 = (unsigned short*)(func + (size_t)SEGS * HDIM);  // N u16

    int chunk = ((N + NBLK - 1) / NBLK + 3) & ~3;  // multiple of 4 for int4 paths

    hist_k<<<NBLK, 256, 0, stream>>>(batch, fid, seg16, hist_t, N, chunk);
    segscan_k<<<SEGS / 4, 256, 0, stream>>>(hist_t, cnt);
    scan_k<<<1, 256, 0, stream>>>(cnt, starts);
    scatter_k<<<NBLK, 256, 0, stream>>>(seg16, hist_t, starts, sorted, N, chunk);
    segreduce_k<<<SEGS, 256, 0, stream>>>((const f32x4*)x, sorted, starts, cnt, feat);
    funcpool_k<<<FNUM, 256, 0, stream>>>(feat, (const float4*)Wf, bfv, func);
    filefinal_k<<<BSZ, 256, 0, stream>>>(func, (const float4*)Wg, bg, out);
}